// Round 1
// baseline (167.381 us; speedup 1.0000x reference)
//
#include <hip/hip_runtime.h>

// GraphAttentionLayer, B=8, N=1024, F_IN=64, HEADS=8, D=64.
// Key algebraic rewrite: exp(leaky_relu(s_i + t_j)) factorizes into
//   [s_i+t_j>0] e^{s_i} e^{t_j} + [s_i+t_j<=0] e^{0.01 s_i} e^{0.01 t_j}
// so both softmax denominators (over i) and the attention-weighted sum over j
// reduce to prefix sums over sorted s / sorted t. O(N^2 D) -> O(N log N + N D).

#define B_  8
#define N_  1024
#define H_  8
#define D_  64
#define BH_ 64

// ---------------- Kernel A: Wh = h@W (row-blocked), s/t = Wh . a ----------
__global__ __launch_bounds__(256) void k_wh(
    const float* __restrict__ h, const float* __restrict__ W,
    const float* __restrict__ a,
    float* __restrict__ Wh, float* __restrict__ sArr, float* __restrict__ tArr) {
  __shared__ float hL[16 * 64];     // 16 rows of h
  __shared__ float whL[16 * 512];   // 16 rows of Wh
  __shared__ float aL[128];
  const int tid = threadIdx.x;
  const int row0 = blockIdx.x * 16;       // flat (b*N + n), 16 rows per block
  const int b = row0 >> 10;
  for (int i = tid; i < 16 * 64; i += 256) hL[i] = h[row0 * 64 + i];
  if (tid < 128) aL[tid] = a[tid];
  __syncthreads();

  float acc0[16], acc1[16];
#pragma unroll
  for (int r = 0; r < 16; ++r) { acc0[r] = 0.f; acc1[r] = 0.f; }
  for (int k = 0; k < 64; ++k) {
    const float w0 = W[k * 512 + tid];
    const float w1 = W[k * 512 + tid + 256];
#pragma unroll
    for (int r = 0; r < 16; ++r) {
      const float hv = hL[r * 64 + k];   // broadcast
      acc0[r] += hv * w0;
      acc1[r] += hv * w1;
    }
  }
  const int hh0 = tid >> 6, d0 = tid & 63;
  const int hh1 = (tid + 256) >> 6;
#pragma unroll
  for (int r = 0; r < 16; ++r) {
    const int n = (row0 + r) & (N_ - 1);
    whL[r * 512 + tid] = acc0[r];
    whL[r * 512 + tid + 256] = acc1[r];
    Wh[((b * H_ + hh0) * N_ + n) * D_ + d0] = acc0[r];
    Wh[((b * H_ + hh1) * N_ + n) * D_ + d0] = acc1[r];
  }
  __syncthreads();
  // s,t: 128 threads, one per (row, head); staggered d to avoid bank conflicts
  if (tid < 128) {
    const int r = tid >> 3, hh = tid & 7;
    const int n = (row0 + r) & (N_ - 1);
    float accS = 0.f, accT = 0.f;
    for (int jj = 0; jj < 64; ++jj) {
      const int d = (jj + tid) & 63;
      const float wv = whL[r * 512 + hh * 64 + d];
      accS += wv * aL[d];
      accT += wv * aL[64 + d];
    }
    sArr[(b * H_ + hh) * N_ + n] = accS;
    tArr[(b * H_ + hh) * N_ + n] = accT;
  }
}

// ---- Kernel B: per (b,h): sort t (w/ idx) & s, exp-scans, Z, u,v, chunk offsets
__global__ __launch_bounds__(1024) void k_sort(
    const float* __restrict__ sArr, const float* __restrict__ tArr,
    const float* __restrict__ Wh,
    float* __restrict__ tsv, int* __restrict__ tsi,
    float* __restrict__ uArr, float* __restrict__ vArr,
    float* __restrict__ cOff1, float* __restrict__ cOff2) {
  __shared__ float tv[1024];
  __shared__ int   ti[1024];
  __shared__ float sv[1024];
  __shared__ float cum1[1024], cum001[1024];
  __shared__ float uL[1024], vL[1024];
  __shared__ float cs1[16 * 64], cs2[16 * 64];
  const int tid = threadIdx.x;
  const int bh = blockIdx.x;
  tv[tid] = tArr[bh * N_ + tid];
  ti[tid] = tid;
  sv[tid] = sArr[bh * N_ + tid];
  __syncthreads();

  // bitonic sort ascending: tv (with ti) and sv
  for (int size = 2; size <= 1024; size <<= 1) {
    for (int stride = size >> 1; stride > 0; stride >>= 1) {
      const int i = tid, j = i ^ stride;
      if (j > i) {
        const bool up = ((i & size) == 0);
        float av = tv[i], bv = tv[j];
        if ((av > bv) == up) {
          tv[i] = bv; tv[j] = av;
          int t_ = ti[i]; ti[i] = ti[j]; ti[j] = t_;
        }
        float as = sv[i], bs = sv[j];
        if ((as > bs) == up) { sv[i] = bs; sv[j] = as; }
      }
      __syncthreads();
    }
  }

  // inclusive scans over exp(s) and exp(0.01 s) in sorted-s order
  cum1[tid] = expf(sv[tid]);
  cum001[tid] = expf(0.01f * sv[tid]);
  __syncthreads();
  for (int off = 1; off < 1024; off <<= 1) {
    float x1 = 0.f, x2 = 0.f;
    if (tid >= off) { x1 = cum1[tid - off]; x2 = cum001[tid - off]; }
    __syncthreads();
    cum1[tid] += x1; cum001[tid] += x2;
    __syncthreads();
  }
  const float totalHi = cum1[1023];

  // per sorted-t rank k: Z, u = e^t/Z, v = e^{0.01t}/Z
  {
    const float tj = tv[tid];
    const float th = -tj;
    int lo = 0, hi = 1024;  // first idx with sv > th  (== count of s <= th)
    while (lo < hi) { const int mid = (lo + hi) >> 1; if (sv[mid] <= th) lo = mid + 1; else hi = mid; }
    const float S_lo = (lo > 0) ? cum001[lo - 1] : 0.f;
    const float S_hi = totalHi - ((lo > 0) ? cum1[lo - 1] : 0.f);
    const float et = expf(tj), et001 = expf(0.01f * tj);
    const float Z = et * S_hi + et001 * S_lo;
    const float u = et / Z, v = et001 / Z;
    uArr[bh * N_ + tid] = u; vArr[bh * N_ + tid] = v;
    tsv[bh * N_ + tid] = tj; tsi[bh * N_ + tid] = ti[tid];
    uL[tid] = u; vL[tid] = v;
  }
  __syncthreads();

  // chunk sums (16 chunks of 64 ranks) of u*Wh and v*Wh, then exclusive offsets
  const int c = tid >> 6, d = tid & 63;
  float s1 = 0.f, s2 = 0.f;
  for (int jj = 0; jj < 64; ++jj) {
    const int k = c * 64 + jj;
    const int j = ti[k];
    const float w = Wh[(bh * N_ + j) * D_ + d];
    s1 += uL[k] * w;
    s2 += vL[k] * w;
  }
  cs1[c * 64 + d] = s1; cs2[c * 64 + d] = s2;
  __syncthreads();
  float o1 = 0.f, o2 = 0.f;
  for (int cc = 0; cc < 16; ++cc) {
    if (cc < c) { o1 += cs1[cc * 64 + d]; o2 += cs2[cc * 64 + d]; }
  }
  cOff1[(bh * 16 + c) * 64 + d] = o1;
  cOff2[(bh * 16 + c) * 64 + d] = o2;
}

// ---- Kernel B4: write full inclusive per-rank prefix vectors INC1/INC2 ----
__global__ __launch_bounds__(64) void k_inc(
    const float* __restrict__ Wh, const int* __restrict__ tsi,
    const float* __restrict__ uArr, const float* __restrict__ vArr,
    const float* __restrict__ cOff1, const float* __restrict__ cOff2,
    float* __restrict__ INC1, float* __restrict__ INC2) {
  const int blk = blockIdx.x;   // bh*16 + chunk
  const int bh = blk >> 4, c = blk & 15;
  const int d = threadIdx.x;
  float r1 = cOff1[blk * 64 + d];
  float r2 = cOff2[blk * 64 + d];
  const int base = bh * N_;
#pragma unroll 4
  for (int jj = 0; jj < 64; ++jj) {
    const int k = c * 64 + jj;
    const int j = tsi[base + k];
    const float u = uArr[base + k], v = vArr[base + k];
    const float w = Wh[(base + j) * D_ + d];
    r1 += u * w;
    r2 += v * w;
    INC1[(base + k) * D_ + d] = r1;
    INC2[(base + k) * D_ + d] = r2;
  }
}

// ---- Kernel C: rank lookup, h' combine, fused projection @ out_W + bias ---
__global__ __launch_bounds__(512) void k_out(
    const float* __restrict__ sArr, const float* __restrict__ tsv,
    const float* __restrict__ INC1, const float* __restrict__ INC2,
    const float* __restrict__ outW, const float* __restrict__ outb,
    float* __restrict__ out) {
  __shared__ float hpL[16 * 512];        // 32 KB: h' rows
  __shared__ float part[8 * 8 * 64];     // 16 KB: projection partials
  __shared__ int   rkI[16 * 8];
  __shared__ float esL[16 * 8], es001L[16 * 8];
  const int tid = threadIdx.x;
  const int row0 = blockIdx.x * 16;
  const int b = row0 >> 10;

  // phase 0: ranks + exp factors, one thread per (row, head)
  if (tid < 128) {
    const int r = tid >> 3, hh = tid & 7;
    const int bh = b * H_ + hh;
    const int n = (row0 + r) & (N_ - 1);
    const float si = sArr[bh * N_ + n];
    const float th = -si;
    const float* tvp = tsv + bh * N_;
    int lo = 0, hi = 1024;  // count of t_j <= -s_i
    while (lo < hi) { const int mid = (lo + hi) >> 1; if (tvp[mid] <= th) lo = mid + 1; else hi = mid; }
    rkI[tid] = lo;
    esL[tid] = expf(si);
    es001L[tid] = expf(0.01f * si);
  }
  __syncthreads();

  // phase 1: h'[r, hh*64+d] = e^s*(T1 - INC1[rk-1]) + e^{0.01 s}*INC2[rk-1]
  {
    const int hh = tid >> 6, d = tid & 63;
    const int bh = b * H_ + hh;
    const float T1 = INC1[(bh * N_ + (N_ - 1)) * D_ + d];
    for (int r = 0; r < 16; ++r) {
      const int rk = rkI[r * 8 + hh];
      float i1 = 0.f, i2 = 0.f;
      if (rk > 0) {
        i1 = INC1[(bh * N_ + rk - 1) * D_ + d];
        i2 = INC2[(bh * N_ + rk - 1) * D_ + d];
      }
      hpL[r * 512 + hh * 64 + d] =
          esL[r * 8 + hh] * (T1 - i1) + es001L[r * 8 + hh] * i2;
    }
  }
  __syncthreads();

  // phase 2: out[row] = h'[row] @ outW + outb   (thread = (cc out-col, p k-slice))
  const int cc = tid & 63, p = tid >> 6;
  float acc[16];
#pragma unroll
  for (int r = 0; r < 16; ++r) acc[r] = 0.f;
  for (int k = p * 64; k < p * 64 + 64; ++k) {
    const float wv = outW[k * 64 + cc];
#pragma unroll
    for (int r = 0; r < 16; ++r) acc[r] += hpL[r * 512 + k] * wv;  // broadcast
  }
  for (int half = 0; half < 2; ++half) {
#pragma unroll
    for (int r = 0; r < 8; ++r) part[(p * 8 + r) * 64 + cc] = acc[half * 8 + r];
    __syncthreads();
    {
      const int r = tid >> 6, c2 = tid & 63;
      float ssum = 0.f;
#pragma unroll
      for (int p2 = 0; p2 < 8; ++p2) ssum += part[(p2 * 8 + r) * 64 + c2];
      out[(row0 + half * 8 + r) * 64 + c2] = outb[c2] + ssum;
    }
    __syncthreads();
  }
}

extern "C" void kernel_launch(void* const* d_in, const int* in_sizes, int n_in,
                              void* d_out, int out_size, void* d_ws, size_t ws_size,
                              hipStream_t stream) {
  const float* h    = (const float*)d_in[0];
  // d_in[1] = adj: unused by the module (all-ones, ignored by reference)
  const float* W    = (const float*)d_in[2];
  const float* a    = (const float*)d_in[3];
  const float* outW = (const float*)d_in[4];
  const float* outb = (const float*)d_in[5];
  float* out = (float*)d_out;

  float* ws   = (float*)d_ws;
  float* Wh   = ws;                                   // BH*N*D = 4,194,304 f
  float* sArr = Wh + (size_t)BH_ * N_ * D_;           // BH*N
  float* tArr = sArr + BH_ * N_;
  float* tsv  = tArr + BH_ * N_;
  int*   tsi  = (int*)(tsv + BH_ * N_);
  float* uArr = (float*)(tsi + BH_ * N_);
  float* vArr = uArr + BH_ * N_;
  float* cOff1 = vArr + BH_ * N_;                     // BH*16*64
  float* cOff2 = cOff1 + BH_ * 16 * 64;
  float* INC1 = cOff2 + BH_ * 16 * 64;                // BH*N*D
  float* INC2 = INC1 + (size_t)BH_ * N_ * D_;
  // total ~52.7 MB of d_ws

  hipLaunchKernelGGL(k_wh,   dim3((B_ * N_) / 16), dim3(256), 0, stream,
                     h, W, a, Wh, sArr, tArr);
  hipLaunchKernelGGL(k_sort, dim3(BH_), dim3(1024), 0, stream,
                     sArr, tArr, Wh, tsv, tsi, uArr, vArr, cOff1, cOff2);
  hipLaunchKernelGGL(k_inc,  dim3(BH_ * 16), dim3(64), 0, stream,
                     Wh, tsi, uArr, vArr, cOff1, cOff2, INC1, INC2);
  hipLaunchKernelGGL(k_out,  dim3((B_ * N_) / 16), dim3(512), 0, stream,
                     sArr, tsv, INC1, INC2, outW, outb, out);
}

// Round 2
// 155.438 us; speedup vs baseline: 1.0768x; 1.0768x over previous
//
#include <hip/hip_runtime.h>

// GraphAttentionLayer, B=8, N=1024, F_IN=64, HEADS=8, D=64.
// exp(leaky_relu(s_i + t_j)) factorizes across the LeakyReLU branch:
//   [s_i+t_j>0] e^{s_i} e^{t_j} + [s_i+t_j<=0] e^{0.01 s_i} e^{0.01 t_j}
// so softmax denominators (over i) and the weighted sum over j reduce to
// prefix sums over sorted s / sorted t.  O(N^2 D) -> O(N log N + N D).
//
// R2 changes: shfl-based bitonic (strides<64 in-register, no barrier),
// shfl-based scans, query ranks precomputed in k_sort, chunk len 64->32
// (k_inc occupancy 4->8 waves/CU, serial chain halved).

#define B_  8
#define N_  1024
#define H_  8
#define D_  64
#define BH_ 64
#define CH_ 32          // chunks per (b,h)
#define CL_ 32          // ranks per chunk

// ---------------- Kernel A: Wh = h@W (row-blocked), s/t = Wh . a ----------
__global__ __launch_bounds__(256) void k_wh(
    const float* __restrict__ h, const float* __restrict__ W,
    const float* __restrict__ a,
    float* __restrict__ Wh, float* __restrict__ sArr, float* __restrict__ tArr) {
  __shared__ float hL[16 * 64];
  __shared__ float whL[16 * 512];
  __shared__ float aL[128];
  const int tid = threadIdx.x;
  const int row0 = blockIdx.x * 16;
  const int b = row0 >> 10;
  for (int i = tid; i < 16 * 64; i += 256) hL[i] = h[row0 * 64 + i];
  if (tid < 128) aL[tid] = a[tid];
  __syncthreads();

  float acc0[16], acc1[16];
#pragma unroll
  for (int r = 0; r < 16; ++r) { acc0[r] = 0.f; acc1[r] = 0.f; }
  for (int k = 0; k < 64; ++k) {
    const float w0 = W[k * 512 + tid];
    const float w1 = W[k * 512 + tid + 256];
#pragma unroll
    for (int r = 0; r < 16; ++r) {
      const float hv = hL[r * 64 + k];
      acc0[r] += hv * w0;
      acc1[r] += hv * w1;
    }
  }
  const int hh0 = tid >> 6, d0 = tid & 63;
  const int hh1 = (tid + 256) >> 6;
#pragma unroll
  for (int r = 0; r < 16; ++r) {
    const int n = (row0 + r) & (N_ - 1);
    whL[r * 512 + tid] = acc0[r];
    whL[r * 512 + tid + 256] = acc1[r];
    Wh[((b * H_ + hh0) * N_ + n) * D_ + d0] = acc0[r];
    Wh[((b * H_ + hh1) * N_ + n) * D_ + d0] = acc1[r];
  }
  __syncthreads();
  if (tid < 128) {
    const int r = tid >> 3, hh = tid & 7;
    const int n = (row0 + r) & (N_ - 1);
    float accS = 0.f, accT = 0.f;
    for (int jj = 0; jj < 64; ++jj) {
      const int d = (jj + tid) & 63;
      const float wv = whL[r * 512 + hh * 64 + d];
      accS += wv * aL[d];
      accT += wv * aL[64 + d];
    }
    sArr[(b * H_ + hh) * N_ + n] = accS;
    tArr[(b * H_ + hh) * N_ + n] = accT;
  }
}

// ---- Kernel B: per (b,h): dual shfl-bitonic sort, shfl scans, Z/u/v,
//      query ranks, chunk sums + exclusive chunk offsets ----
__global__ __launch_bounds__(1024) void k_sort(
    const float* __restrict__ sArr, const float* __restrict__ tArr,
    const float* __restrict__ Wh,
    int* __restrict__ tsi, float* __restrict__ uArr, float* __restrict__ vArr,
    int* __restrict__ qrk,
    float* __restrict__ cOff1, float* __restrict__ cOff2) {
  __shared__ float sL[1024];
  __shared__ float tvL[1024];
  __shared__ int   tiL[1024];
  __shared__ float cum1L[1024], cum001L[1024];
  __shared__ float uL[1024], vL[1024];
  __shared__ float cs1[CH_ * 64], cs2[CH_ * 64];
  __shared__ float ws1[16], ws2[16];
  const int tid = threadIdx.x;
  const int lane = tid & 63;
  const int wv_ = tid >> 6;
  const int bh = blockIdx.x;

  const float orig_s = sArr[bh * N_ + tid];
  float sv_r = orig_s;
  float tv_r = tArr[bh * N_ + tid];
  int   ti_r = tid;

  // bitonic sort ascending; strides<64 via shfl (no barrier), >=64 via LDS
  for (int size = 2; size <= 1024; size <<= 1) {
    for (int stride = size >> 1; stride > 0; stride >>= 1) {
      const bool up = ((tid & size) == 0);
      const bool lower = ((tid & stride) == 0);
      float psv, ptv; int pti;
      if (stride >= 64) {
        sL[tid] = sv_r; tvL[tid] = tv_r; tiL[tid] = ti_r;
        __syncthreads();
        const int p = tid ^ stride;
        psv = sL[p]; ptv = tvL[p]; pti = tiL[p];
        __syncthreads();
      } else {
        psv = __shfl_xor(sv_r, stride);
        ptv = __shfl_xor(tv_r, stride);
        pti = __shfl_xor(ti_r, stride);
      }
      const bool sameDir = (up == lower);
      // s: value-only (ties harmless)
      const bool pLessS = (psv < sv_r);
      if (pLessS == sameDir) sv_r = psv;
      // t: lexicographic (value, idx) for a strict total order
      const bool pLessT = (ptv < tv_r) || (ptv == tv_r && pti < ti_r);
      if (pLessT == sameDir) { tv_r = ptv; ti_r = pti; }
    }
  }
  sL[tid] = sv_r; tvL[tid] = tv_r; tiL[tid] = ti_r;

  // inclusive scans of exp(s), exp(0.01 s) in sorted order: wave scan + fixup
  float c1 = __expf(sv_r) , c001 = __expf(0.01f * sv_r);
  {
    float a1 = c1, a2 = c001;
#pragma unroll
    for (int off = 1; off < 64; off <<= 1) {
      const float x1 = __shfl_up(a1, off);
      const float x2 = __shfl_up(a2, off);
      if (lane >= off) { a1 += x1; a2 += x2; }
    }
    if (lane == 63) { ws1[wv_] = a1; ws2[wv_] = a2; }
    __syncthreads();
    float o1 = 0.f, o2 = 0.f;
    for (int ww = 0; ww < 16; ++ww) {
      if (ww < wv_) { o1 += ws1[ww]; o2 += ws2[ww]; }
    }
    c1 = a1 + o1; c001 = a2 + o2;
  }
  cum1L[tid] = c1; cum001L[tid] = c001;
  __syncthreads();
  const float totalHi = cum1L[1023];

  // per sorted-t rank: Z, u = e^t/Z, v = e^{0.01t}/Z
  {
    const float tj = tv_r;
    const float th = -tj;
    int lo = 0, hi = 1024;   // count of sorted-s <= th
    while (lo < hi) { const int mid = (lo + hi) >> 1; if (sL[mid] <= th) lo = mid + 1; else hi = mid; }
    const float S_lo = (lo > 0) ? cum001L[lo - 1] : 0.f;
    const float S_hi = totalHi - ((lo > 0) ? cum1L[lo - 1] : 0.f);
    const float et = __expf(tj), et001 = __expf(0.01f * tj);
    const float Z = et * S_hi + et001 * S_lo;
    const float u = et / Z, v = et001 / Z;
    uL[tid] = u; vL[tid] = v;
    uArr[bh * N_ + tid] = u; vArr[bh * N_ + tid] = v;
    tsi[bh * N_ + tid] = ti_r;
  }

  // query rank for row i=tid: count of t_j <= -s_i (value-only, ties ok)
  {
    const float th = -orig_s;
    int lo = 0, hi = 1024;
    while (lo < hi) { const int mid = (lo + hi) >> 1; if (tvL[mid] <= th) lo = mid + 1; else hi = mid; }
    qrk[bh * N_ + tid] = lo;
  }
  __syncthreads();

  // chunk sums (CH_ chunks of CL_ ranks) of u*Wh, v*Wh + exclusive offsets
  const int c = tid >> 6, d = tid & 63;
#pragma unroll
  for (int half = 0; half < 2; ++half) {
    const int cc = c + half * 16;
    float s1 = 0.f, s2 = 0.f;
    for (int k2 = 0; k2 < CL_; ++k2) {
      const int k = cc * CL_ + k2;
      const int j = tiL[k];
      const float w = Wh[(bh * N_ + j) * D_ + d];
      s1 += uL[k] * w;
      s2 += vL[k] * w;
    }
    cs1[cc * 64 + d] = s1; cs2[cc * 64 + d] = s2;
  }
  __syncthreads();
#pragma unroll
  for (int half = 0; half < 2; ++half) {
    const int cc = c + half * 16;
    float o1 = 0.f, o2 = 0.f;
    for (int m = 0; m < cc; ++m) { o1 += cs1[m * 64 + d]; o2 += cs2[m * 64 + d]; }
    cOff1[(bh * CH_ + cc) * 64 + d] = o1;
    cOff2[(bh * CH_ + cc) * 64 + d] = o2;
  }
}

// ---- Kernel C: inclusive per-rank prefix vectors INC1/INC2 (chunk len 32) --
__global__ __launch_bounds__(64) void k_inc(
    const float* __restrict__ Wh, const int* __restrict__ tsi,
    const float* __restrict__ uArr, const float* __restrict__ vArr,
    const float* __restrict__ cOff1, const float* __restrict__ cOff2,
    float* __restrict__ INC1, float* __restrict__ INC2) {
  const int blk = blockIdx.x;            // bh*CH_ + chunk
  const int bh = blk >> 5, c = blk & (CH_ - 1);
  const int d = threadIdx.x;
  float r1 = cOff1[blk * 64 + d];
  float r2 = cOff2[blk * 64 + d];
  const int base = bh * N_;
#pragma unroll 8
  for (int k2 = 0; k2 < CL_; ++k2) {
    const int k = c * CL_ + k2;
    const int j = tsi[base + k];
    const float u = uArr[base + k], v = vArr[base + k];
    const float w = Wh[(base + j) * D_ + d];
    r1 += u * w;
    r2 += v * w;
    INC1[(base + k) * D_ + d] = r1;
    INC2[(base + k) * D_ + d] = r2;
  }
}

// ---- Kernel C2: rank lookup (precomputed), h' combine, fused @ out_W + b --
__global__ __launch_bounds__(512) void k_out(
    const float* __restrict__ sArr, const int* __restrict__ qrk,
    const float* __restrict__ INC1, const float* __restrict__ INC2,
    const float* __restrict__ outW, const float* __restrict__ outb,
    float* __restrict__ out) {
  __shared__ float hpL[16 * 512];
  __shared__ float part[8 * 8 * 64];
  __shared__ int   rkI[16 * 8];
  __shared__ float esL[16 * 8], es001L[16 * 8];
  const int tid = threadIdx.x;
  const int row0 = blockIdx.x * 16;
  const int b = row0 >> 10;

  if (tid < 128) {
    const int r = tid >> 3, hh = tid & 7;
    const int bh = b * H_ + hh;
    const int n = (row0 + r) & (N_ - 1);
    const float si = sArr[bh * N_ + n];
    rkI[tid] = qrk[bh * N_ + n];
    esL[tid] = __expf(si);
    es001L[tid] = __expf(0.01f * si);
  }
  __syncthreads();

  {
    const int hh = tid >> 6, d = tid & 63;
    const int bh = b * H_ + hh;
    const float T1 = INC1[(bh * N_ + (N_ - 1)) * D_ + d];
    for (int r = 0; r < 16; ++r) {
      const int rk = rkI[r * 8 + hh];
      float i1 = 0.f, i2 = 0.f;
      if (rk > 0) {
        i1 = INC1[(bh * N_ + rk - 1) * D_ + d];
        i2 = INC2[(bh * N_ + rk - 1) * D_ + d];
      }
      hpL[r * 512 + hh * 64 + d] =
          esL[r * 8 + hh] * (T1 - i1) + es001L[r * 8 + hh] * i2;
    }
  }
  __syncthreads();

  const int cc = tid & 63, p = tid >> 6;
  float acc[16];
#pragma unroll
  for (int r = 0; r < 16; ++r) acc[r] = 0.f;
  for (int k = p * 64; k < p * 64 + 64; ++k) {
    const float wvv = outW[k * 64 + cc];
#pragma unroll
    for (int r = 0; r < 16; ++r) acc[r] += hpL[r * 512 + k] * wvv;
  }
  for (int half = 0; half < 2; ++half) {
#pragma unroll
    for (int r = 0; r < 8; ++r) part[(p * 8 + r) * 64 + cc] = acc[half * 8 + r];
    __syncthreads();
    {
      const int r = tid >> 6, c2 = tid & 63;
      float ssum = 0.f;
#pragma unroll
      for (int p2 = 0; p2 < 8; ++p2) ssum += part[(p2 * 8 + r) * 64 + c2];
      out[(row0 + half * 8 + r) * 64 + c2] = outb[c2] + ssum;
    }
    __syncthreads();
  }
}

extern "C" void kernel_launch(void* const* d_in, const int* in_sizes, int n_in,
                              void* d_out, int out_size, void* d_ws, size_t ws_size,
                              hipStream_t stream) {
  const float* h    = (const float*)d_in[0];
  // d_in[1] = adj: all-ones, unused by the module
  const float* W    = (const float*)d_in[2];
  const float* a    = (const float*)d_in[3];
  const float* outW = (const float*)d_in[4];
  const float* outb = (const float*)d_in[5];
  float* out = (float*)d_out;

  float* ws   = (float*)d_ws;
  float* Wh   = ws;                                   // BH*N*D
  float* sArr = Wh + (size_t)BH_ * N_ * D_;           // BH*N
  float* tArr = sArr + BH_ * N_;
  int*   tsi  = (int*)(tArr + BH_ * N_);
  float* uArr = (float*)(tsi + BH_ * N_);
  float* vArr = uArr + BH_ * N_;
  int*   qrk  = (int*)(vArr + BH_ * N_);
  float* cOff1 = (float*)(qrk + BH_ * N_);            // BH*CH_*64
  float* cOff2 = cOff1 + BH_ * CH_ * 64;
  float* INC1 = cOff2 + BH_ * CH_ * 64;               // BH*N*D
  float* INC2 = INC1 + (size_t)BH_ * N_ * D_;

  hipLaunchKernelGGL(k_wh,   dim3((B_ * N_) / 16), dim3(256), 0, stream,
                     h, W, a, Wh, sArr, tArr);
  hipLaunchKernelGGL(k_sort, dim3(BH_), dim3(1024), 0, stream,
                     sArr, tArr, Wh, tsi, uArr, vArr, qrk, cOff1, cOff2);
  hipLaunchKernelGGL(k_inc,  dim3(BH_ * CH_), dim3(64), 0, stream,
                     Wh, tsi, uArr, vArr, cOff1, cOff2, INC1, INC2);
  hipLaunchKernelGGL(k_out,  dim3((B_ * N_) / 16), dim3(512), 0, stream,
                     sArr, qrk, INC1, INC2, outW, outb, out);
}